// Round 2
// baseline (473.993 us; speedup 1.0000x reference)
//
#include <hip/hip_runtime.h>
#include <stdint.h>

// Mamba-1.4B-like dims (fixed)
#define LSEQ 2048
#define HID  2048
#define IDIM 4096
#define NSTATE 16
#define RRANK 128
#define GDIM 160   // RRANK + 2*NSTATE

// chunked scan
#define GCHUNK 64
#define TCHUNK (LSEQ / GCHUNK)   // 32

typedef _Float16 f16x8 __attribute__((ext_vector_type(8)));
typedef _Float16 f16x2 __attribute__((ext_vector_type(2)));
typedef float f32x4 __attribute__((ext_vector_type(4)));

#define GLOAD_LDS16(g, l) __builtin_amdgcn_global_load_lds( \
    (const __attribute__((address_space(1))) void*)(g),     \
    (__attribute__((address_space(3))) void*)(l), 16, 0, 0)

__device__ __forceinline__ float softplus_f(float x) {
    if (x > 20.f) return x;
    return log1pf(__expf(x));
}
__device__ __forceinline__ float silu_f(float x) {
    return x / (1.f + __expf(-x));
}

// ---------------------------------------------------------------------------
// transpose one 64x64 tile of f32 (R x C) -> f16 (C x R)
__device__ __forceinline__ void transpose_tile(const float* __restrict__ in,
                                               _Float16* __restrict__ out,
                                               int R, int C, int tr, int tc,
                                               _Float16 (*tile)[66], int t) {
    const int c0 = tc * 64, r0 = tr * 64;
    const int tx = t & 15, ty = t >> 4;
    const int ox = t & 7, oy = t >> 3;
    const bool full = (c0 + 64 <= C) && (r0 + 64 <= R);
    if (full) {
        #pragma unroll
        for (int j = 0; j < 4; ++j) {
            int r = ty + j * 16;
            float4 v = *(const float4*)(in + (long)(r0 + r) * C + c0 + tx * 4);
            tile[r][tx * 4 + 0] = (_Float16)v.x;
            tile[r][tx * 4 + 1] = (_Float16)v.y;
            tile[r][tx * 4 + 2] = (_Float16)v.z;
            tile[r][tx * 4 + 3] = (_Float16)v.w;
        }
        __syncthreads();
        #pragma unroll
        for (int j = 0; j < 2; ++j) {
            int c = oy + j * 32;
            f16x8 v;
            #pragma unroll
            for (int e = 0; e < 8; ++e) v[e] = tile[ox * 8 + e][c];
            *(f16x8*)(out + (long)(c0 + c) * R + r0 + ox * 8) = v;
        }
    } else {
        #pragma unroll
        for (int j = 0; j < 4; ++j) {
            int r = ty + j * 16;
            #pragma unroll
            for (int e = 0; e < 4; ++e) {
                int c = c0 + tx * 4 + e;
                float v = (r0 + r < R && c < C) ? in[(long)(r0 + r) * C + c] : 0.f;
                tile[r][tx * 4 + e] = (_Float16)v;
            }
        }
        __syncthreads();
        #pragma unroll
        for (int j = 0; j < 2; ++j) {
            int c = c0 + oy + j * 32;
            if (c < C) {
                #pragma unroll
                for (int e = 0; e < 8; ++e) {
                    int r = r0 + ox * 8 + e;
                    if (r < R) out[(long)c * R + r] = tile[ox * 8 + e][oy + j * 32];
                }
            }
        }
    }
}

// ---------------------------------------------------------------------------
// prep: ALL transposes (Wt1/Wt2/Wt3/Wt4) + X f32->f16, high-occupancy BW-bound.
// 4096 + 1024 + 192 + 128 + 2048 = 7488 blocks.
__global__ __launch_bounds__(256)
void prep_kernel(const float* __restrict__ x_in, const float* __restrict__ w_in,
                 const float* __restrict__ xw, const float* __restrict__ dtw,
                 const float* __restrict__ ow,
                 _Float16* __restrict__ Xf, _Float16* __restrict__ Wt1,
                 _Float16* __restrict__ Wt2, _Float16* __restrict__ Wt3,
                 _Float16* __restrict__ Wt4) {
    __shared__ _Float16 tile[64][66];
    int b = blockIdx.x;
    if (b < 4096) { transpose_tile(w_in, Wt1, HID, 2 * IDIM, b / 128, b % 128, tile, threadIdx.x); return; }
    b -= 4096;
    if (b < 1024) {
        long base = (long)b * 4096 + threadIdx.x * 16;
        #pragma unroll
        for (int h = 0; h < 2; ++h) {
            float4 a = *(const float4*)(x_in + base + h * 8);
            float4 c = *(const float4*)(x_in + base + h * 8 + 4);
            f16x8 v;
            v[0] = (_Float16)a.x; v[1] = (_Float16)a.y; v[2] = (_Float16)a.z; v[3] = (_Float16)a.w;
            v[4] = (_Float16)c.x; v[5] = (_Float16)c.y; v[6] = (_Float16)c.z; v[7] = (_Float16)c.w;
            *(f16x8*)(Xf + base + h * 8) = v;
        }
        return;
    }
    b -= 1024;
    if (b < 192) { transpose_tile(xw, Wt2, IDIM, GDIM, b / 3, b % 3, tile, threadIdx.x); return; }
    b -= 192;
    if (b < 128) { transpose_tile(dtw, Wt3, RRANK, IDIM, b / 64, b % 64, tile, threadIdx.x); return; }
    b -= 128;
    transpose_tile(ow, Wt4, IDIM, HID, b / 32, b % 32, tile, threadIdx.x);
}

// ---------------------------------------------------------------------------
// OLD GEMM core (kept for xproj / dtproj skinny shapes):
// C = A(M,K) @ Bt(N,K)^T, fp16 in, fp32 acc. BM=128, BN=128, BK=64.
#define BM 128
#define BK 64

template <typename CT, bool SOFTPLUS>
__device__ __forceinline__
void gemm_core(const _Float16* __restrict__ A, const _Float16* __restrict__ Bt,
               CT* __restrict__ C, int M, int N, int K, int kc,
               const float* __restrict__ bias,
               _Float16* __restrict__ As, _Float16* __restrict__ Bs,
               int m0, int n0, int zz) {
    const int t = threadIdx.x;
    const int wave = t >> 6;
    const int lane = t & 63;
    const int wm = wave >> 1, wn = wave & 1;
    const int lrow = lane & 15;
    const int quad = lane >> 4;
    const int sw8 = (lrow & 7) * 8;

    f32x4 acc[4][4];
    #pragma unroll
    for (int mi = 0; mi < 4; ++mi)
        #pragma unroll
        for (int ni = 0; ni < 4; ++ni)
            #pragma unroll
            for (int r = 0; r < 4; ++r)
                acc[mi][ni][r] = 0.f;

    const int k_begin = zz * kc;
    const _Float16* pA[4];
    const _Float16* pB[4];
    #pragma unroll
    for (int j = 0; j < 4; ++j) {
        int s = j * 256 + t;
        int row = s >> 3;
        int ch = (s & 7) ^ (row & 7);
        pA[j] = A + (long)(m0 + row) * K + ch * 8 + k_begin;
        pB[j] = Bt + (long)(n0 + row) * K + ch * 8 + k_begin;
    }

    for (int kk = 0; kk < kc; kk += BK) {
        #pragma unroll
        for (int j = 0; j < 4; ++j) {
            GLOAD_LDS16(pA[j], As + (j * 256 + wave * 64) * 8);
            pA[j] += BK;
            GLOAD_LDS16(pB[j], Bs + (j * 256 + wave * 64) * 8);
            pB[j] += BK;
        }
        __syncthreads();

        #pragma unroll
        for (int h = 0; h < 2; ++h) {
            const int qoff = (h * 32 + quad * 8) ^ sw8;
            f16x8 af[4], bf[4];
            #pragma unroll
            for (int mi = 0; mi < 4; ++mi)
                af[mi] = *(const f16x8*)(As + (wm * 64 + mi * 16 + lrow) * BK + qoff);
            #pragma unroll
            for (int ni = 0; ni < 4; ++ni)
                bf[ni] = *(const f16x8*)(Bs + (wn * 64 + ni * 16 + lrow) * BK + qoff);
            #pragma unroll
            for (int mi = 0; mi < 4; ++mi)
                #pragma unroll
                for (int ni = 0; ni < 4; ++ni)
                    acc[mi][ni] = __builtin_amdgcn_mfma_f32_16x16x32_f16(af[mi], bf[ni], acc[mi][ni], 0, 0, 0);
        }
        __syncthreads();
    }

    CT* Cz = C + (long)zz * M * N;
    #pragma unroll
    for (int mi = 0; mi < 4; ++mi) {
        #pragma unroll
        for (int ni = 0; ni < 4; ++ni) {
            int col = n0 + wn * 64 + ni * 16 + lrow;
            if (col < N) {
                float bv = SOFTPLUS ? bias[col] : 0.f;
                #pragma unroll
                for (int r = 0; r < 4; ++r) {
                    int row = m0 + wm * 64 + mi * 16 + quad * 4 + r;
                    float v = acc[mi][ni][r];
                    if (SOFTPLUS) v = softplus_f(v + bv);
                    Cz[(long)row * N + col] = (CT)v;
                }
            }
        }
    }
}

// standalone GEMM wrapper (xproj / dtproj)
template <typename CT, bool SOFTPLUS>
__global__ __launch_bounds__(256)
void gemm_bt_kernel(const _Float16* __restrict__ A, const _Float16* __restrict__ Bt,
                    CT* __restrict__ C, int M, int N, int K, int kc,
                    const float* __restrict__ bias) {
    __shared__ _Float16 As[BM * BK];
    __shared__ _Float16 Bs[128 * BK];
    gemm_core<CT, SOFTPLUS>(A, Bt, C, M, N, K, kc, bias, As, Bs,
                            blockIdx.y * BM, blockIdx.x * 128, blockIdx.z);
}

// ---------------------------------------------------------------------------
// 256x256 deep-pipelined GEMM core, ring of 4 K=32 slices, counted vmcnt(8).
// LDS layout (per slice, per operand, 8192 elem): 128 lines x 64 elem (128B).
// Line l holds rows {2l, 2l+1}; 16B sub-chunk s of line l holds (parity p,
// k-chunk c) with (c + 4p) = s ^ (l & 7).  => row-major read for (row r,
// chunk q) at elem  (r>>1)*64 + (((q + 4*(r&1)) ^ ((r>>1)&7)) * 8.
// This reproduces the proven conflict-free distribution (8 lanes per 16B
// slot spanning all 32 banks) of the 128B-row XOR swizzle; the inverse
// permutation is baked into each thread's global source address so the
// gload_lds destination stays linear (both-sides-or-neither).
template <typename CT>
__device__ __forceinline__
void gemm256_core(const _Float16* __restrict__ A, const _Float16* __restrict__ Bt,
                  CT* __restrict__ C, int M, int N, int K, int kc,
                  int m0, int n0, int zz, _Float16* __restrict__ sm) {
    const int t = threadIdx.x;
    const int wave = t >> 6, lane = t & 63;
    const int wm = wave >> 2, wn = wave & 3;
    const int lrow = lane & 15, quad = lane >> 4;
    const int ns = kc >> 5;              // K=32 slices

    // staging source: thread t stages line l0 = t>>3, sub-chunk s = t&7
    const int l0 = t >> 3;                         // 0..63
    const int e  = (t & 7) ^ (l0 & 7);             // = c + 4p
    const int sp = e >> 2, sc = e & 3;             // parity, k-chunk
    const int rowA = 2 * l0 + sp;                  // pass-0 tile row
    const _Float16* gA0 = A  + (size_t)(m0 + rowA) * K + (size_t)zz * kc + sc * 8;
    const _Float16* gA1 = gA0 + (size_t)128 * K;   // pass-1 (rows +128)
    const _Float16* gB0 = Bt + (size_t)(n0 + rowA) * K + (size_t)zz * kc + sc * 8;
    const _Float16* gB1 = gB0 + (size_t)128 * K;

    _Float16* const bsm = sm + 32768;    // B region (elements)
    const int dA = wave * 512;           // wave-uniform LDS dest (elements)

    f32x4 acc[8][4];
    #pragma unroll
    for (int mi = 0; mi < 8; ++mi)
        #pragma unroll
        for (int ni = 0; ni < 4; ++ni)
            #pragma unroll
            for (int r = 0; r < 4; ++r) acc[mi][ni][r] = 0.f;

    #define ISSUE_SLICE(slot) do {                                          \
        _Float16* as_ = sm  + (slot) * 8192;                                \
        _Float16* bs_ = bsm + (slot) * 8192;                                \
        GLOAD_LDS16(gA0, as_ + dA);                                         \
        GLOAD_LDS16(gA1, as_ + 4096 + dA);                                  \
        GLOAD_LDS16(gB0, bs_ + dA);                                         \
        GLOAD_LDS16(gB1, bs_ + 4096 + dA);                                  \
        gA0 += 32; gA1 += 32; gB0 += 32; gB1 += 32;                         \
    } while (0)

    // prologue: 3 slices in flight, wait slice 0 (8 newer loads outstanding)
    ISSUE_SLICE(0); ISSUE_SLICE(1); ISSUE_SLICE(2);
    asm volatile("s_waitcnt vmcnt(8)" ::: "memory");
    __builtin_amdgcn_s_barrier();
    __builtin_amdgcn_sched_barrier(0);

    const int hl = lrow >> 1;                                    // 0..7
    const int koff = ((quad + 4 * (lrow & 1)) ^ hl) * 8;         // swizzled 16B slot
    const int arow0 = wm * 4096 + hl * 64 + koff;
    const int brow0 = wn * 2048 + hl * 64 + koff;

    for (int s2 = 0; s2 < ns; ++s2) {
        const _Float16* as_ = sm  + (s2 & 3) * 8192;
        const _Float16* bs_ = bsm + (s2 & 3) * 8192;
        if (s2 + 3 < ns) ISSUE_SLICE((s2 + 3) & 3);
        __builtin_amdgcn_sched_barrier(0);   // pin issue before ds_reads

        f16x8 af[8], bf[4];
        #pragma unroll
        for (int mi = 0; mi < 8; ++mi)
            af[mi] = *(const f16x8*)(as_ + arow0 + mi * 512);
        #pragma unroll
        for (int ni = 0; ni < 4; ++ni)
            bf[ni] = *(const f16x8*)(bs_ + brow0 + ni * 512);

        __builtin_amdgcn_s_setprio(1);
        #pragma unroll
        for (int mi = 0; mi < 8; ++mi)
            #pragma unroll
            for (int ni = 0; ni < 4; ++ni)
                acc[mi][ni] = __builtin_amdgcn_mfma_f32_16x16x32_f16(af[mi], bf[ni], acc[mi][ni], 0, 0, 0);
        __builtin_amdgcn_s_setprio(0);

        if (s2 + 1 < ns) {
            // need slice s2+1 landed; issued up to min(s2+3, ns-1)
            if (s2 + 4 <= ns)      asm volatile("s_waitcnt vmcnt(8)" ::: "memory");
            else if (s2 + 3 == ns) asm volatile("s_waitcnt vmcnt(4)" ::: "memory");
            else                   asm volatile("s_waitcnt vmcnt(0)" ::: "memory");
            __builtin_amdgcn_s_barrier();
            __builtin_amdgcn_sched_barrier(0);
        }
    }
    #undef ISSUE_SLICE

    CT* Cz = C + (size_t)zz * ((size_t)M * N);
    const int crow = m0 + wm * 128 + quad * 4;
    const int ccol = n0 + wn * 64 + lrow;
    #pragma unroll
    for (int mi = 0; mi < 8; ++mi)
        #pragma unroll
        for (int ni = 0; ni < 4; ++ni)
            #pragma unroll
            for (int r = 0; r < 4; ++r)
                Cz[(size_t)(crow + mi * 16 + r) * N + ccol + ni * 16] = (CT)acc[mi][ni][r];
}

// out_proj split-K x4 wrapper: grid dim3(N/256, M/256, 4), f32 partials
__global__ __launch_bounds__(512, 2)
void gemm256_kernel(const _Float16* __restrict__ A, const _Float16* __restrict__ Bt,
                    float* __restrict__ C, int M, int N, int K, int kc) {
    __shared__ _Float16 sm[65536];   // 128 KiB
    int nb = gridDim.x * gridDim.y * gridDim.z;
    int f0 = blockIdx.x + gridDim.x * (blockIdx.y + gridDim.y * blockIdx.z);
    int cpx = nb >> 3;                              // blocks per XCD (nb % 8 == 0)
    int f = (f0 & 7) * cpx + (f0 >> 3);             // bijective XCD swizzle
    int bx = f % gridDim.x;
    int r2 = f / gridDim.x;
    int by = r2 % gridDim.y;
    int bz = r2 / gridDim.y;
    gemm256_core<float>(A, Bt, C, M, N, K, kc, by * 256, bx * 256, bz, sm);
}

// in_proj: pure 256-block 256^2 GEMM (1 block/CU)
__global__ __launch_bounds__(512, 2)
void inproj256_kernel(const _Float16* __restrict__ Xf, const _Float16* __restrict__ Wt1,
                      _Float16* __restrict__ proj) {
    __shared__ _Float16 sm[65536];   // 128 KiB
    int b = blockIdx.x;
    // XCD swizzle: XCD x owns tile-row x (A-panel stays in its L2)
    int f = (b & 7) * 32 + (b >> 3);
    gemm256_core<_Float16>(Xf, Wt1, proj, LSEQ, 2 * IDIM, HID, HID,
                           (f >> 5) * 256, (f & 31) * 256, 0, sm);
}

// ---------------------------------------------------------------------------
// x_proj split-K reduce: sum 16 partial slabs (L,256), write ssm (L,160) f32
// and dt_in (L,128) f16.
__global__ void xproj_reduce_kernel(const float* __restrict__ part, float* __restrict__ ssm,
                                    _Float16* __restrict__ dtin) {
    int idx = blockIdx.x * 256 + threadIdx.x;
    if (idx >= LSEQ * GDIM) return;
    int t = idx / GDIM;
    int c = idx - t * GDIM;
    float v = 0.f;
    #pragma unroll
    for (int k = 0; k < 16; ++k)
        v += part[((long)k * LSEQ + t) * 256 + c];
    ssm[idx] = v;
    if (c < RRANK) dtin[t * RRANK + c] = (_Float16)v;
}

// ---------------------------------------------------------------------------
// out_proj split-K reduce (f32 partials x4): out = p0+p1+p2+p3
__global__ void opart_reduce_kernel(const float* __restrict__ part, float* __restrict__ out) {
    size_t base = ((size_t)blockIdx.x * 256 + threadIdx.x) * 32;
    const size_t SL = (size_t)LSEQ * HID;
    #pragma unroll
    for (int j = 0; j < 8; ++j) {
        float4 a = *(const float4*)(part + base + j * 4);
        float4 b = *(const float4*)(part + SL + base + j * 4);
        float4 c = *(const float4*)(part + 2 * SL + base + j * 4);
        float4 d = *(const float4*)(part + 3 * SL + base + j * 4);
        float4 o = make_float4(a.x + b.x + c.x + d.x,
                               a.y + b.y + c.y + d.y,
                               a.z + b.z + c.z + d.z,
                               a.w + b.w + c.w + d.w);
        *(float4*)(out + base + j * 4) = o;
    }
}

// ---------------------------------------------------------------------------
// depthwise causal conv (K=4) + bias + SiLU; 8 channels x 4 timesteps/thread
__global__ void conv_silu_kernel(const _Float16* __restrict__ proj, const float* __restrict__ w,
                                 const float* __restrict__ b, _Float16* __restrict__ u16) {
    int idx = blockIdx.x * 256 + threadIdx.x;   // (L/4) * (I/8)
    int i0 = (idx & 511) * 8;
    int t0 = (idx >> 9) * 4;
    f16x8 r[7];
    #pragma unroll
    for (int k = 0; k < 7; ++k) {
        int tt = t0 - 3 + k;
        if (tt >= 0) r[k] = *(const f16x8*)(proj + (long)tt * (2 * IDIM) + i0);
        else         r[k] = f16x8{0,0,0,0,0,0,0,0};
    }
    float4 wv[8]; float bb[8];
    #pragma unroll
    for (int j = 0; j < 8; ++j) { wv[j] = ((const float4*)w)[i0 + j]; bb[j] = b[i0 + j]; }
    #pragma unroll
    for (int tt = 0; tt < 4; ++tt) {
        f16x8 res;
        #pragma unroll
        for (int j = 0; j < 8; ++j) {
            float a = bb[j] + (float)r[tt][j] * wv[j].x + (float)r[tt+1][j] * wv[j].y
                            + (float)r[tt+2][j] * wv[j].z + (float)r[tt+3][j] * wv[j].w;
            res[j] = (_Float16)(a / (1.f + __expf(-a)));
        }
        *(f16x8*)(u16 + (long)(t0 + tt) * IDIM + i0) = res;
    }
}

// ---------------------------------------------------------------------------
// Chunked selective scan, 2 channels/thread, f16 chunk states.
__global__ __launch_bounds__(256)
void scan_pass1_kernel(const _Float16* __restrict__ dtf, const float* __restrict__ ssm,
                       const _Float16* __restrict__ u16, const float* __restrict__ A_log,
                       _Float16* __restrict__ Pc, _Float16* __restrict__ Sc) {
    const int c = blockIdx.y;
    const int i0 = (blockIdx.x * 256 + threadIdx.x) * 2;

    __shared__ float Bs[TCHUNK * 16];
    for (int idx = threadIdx.x; idx < TCHUNK * 16; idx += 256) {
        int t = idx >> 4, n = idx & 15;
        Bs[idx] = ssm[(c * TCHUNK + t) * GDIM + RRANK + n];
    }
    __syncthreads();

    float A[2][16];
    #pragma unroll
    for (int ch = 0; ch < 2; ++ch) {
        const float4* Ap = (const float4*)(A_log + (long)(i0 + ch) * 16);
        #pragma unroll
        for (int q = 0; q < 4; ++q) {
            float4 v = Ap[q];
            A[ch][q * 4 + 0] = -__expf(v.x);
            A[ch][q * 4 + 1] = -__expf(v.y);
            A[ch][q * 4 + 2] = -__expf(v.z);
            A[ch][q * 4 + 3] = -__expf(v.w);
        }
    }

    float s[2][16];
    float sumdt[2] = {0.f, 0.f};
    #pragma unroll
    for (int ch = 0; ch < 2; ++ch)
        #pragma unroll
        for (int n = 0; n < 16; ++n) s[ch][n] = 0.f;

    long base = (long)c * TCHUNK * IDIM + i0;
    for (int t = 0; t < TCHUNK; ++t) {
        f16x2 dt2 = *(const f16x2*)(dtf + base + (long)t * IDIM);
        f16x2 u2  = *(const f16x2*)(u16 + base + (long)t * IDIM);
        #pragma unroll
        for (int ch = 0; ch < 2; ++ch) {
            float dt = (float)dt2[ch];
            float dtu = dt * (float)u2[ch];
            sumdt[ch] += dt;
            #pragma unroll
            for (int n = 0; n < 16; ++n) {
                float dA = __expf(dt * A[ch][n]);
                s[ch][n] = s[ch][n] * dA + dtu * Bs[t * 16 + n];
            }
        }
    }

    long o = ((long)c * IDIM + i0) * 16;
    #pragma unroll
    for (int ch = 0; ch < 2; ++ch) {
        #pragma unroll
        for (int q = 0; q < 2; ++q) {
            f16x8 pv, sv;
            #pragma unroll
            for (int e = 0; e < 8; ++e) {
                pv[e] = (_Float16)__expf(A[ch][q * 8 + e] * sumdt[ch]);
                sv[e] = (_Float16)s[ch][q * 8 + e];
            }
            *(f16x8*)(Pc + o + ch * 16 + q * 8) = pv;
            *(f16x8*)(Sc + o + ch * 16 + q * 8) = sv;
        }
    }
}

// Combine: sequential over G chunks per (i,n) pair, f32 carry, group-of-4 prefetch.
__global__ void scan_combine_kernel(const _Float16* __restrict__ Pc, _Float16* __restrict__ ScInit) {
    int tid = blockIdx.x * 256 + threadIdx.x;   // I*16/2 pairs
    const long stride = (long)IDIM * 16;
    const long off = (long)tid * 2;
    f16x2 p4[4], s4[4];
    #pragma unroll
    for (int k = 0; k < 4; ++k) {
        p4[k] = *(const f16x2*)(Pc + (long)k * stride + off);
        s4[k] = *(const f16x2*)(ScInit + (long)k * stride + off);
    }
    float c0 = 0.f, c1 = 0.f;
    for (int g = 0; g < GCHUNK / 4; ++g) {
        f16x2 pc[4], sc[4];
        #pragma unroll
        for (int k = 0; k < 4; ++k) { pc[k] = p4[k]; sc[k] = s4[k]; }
        if (g + 1 < GCHUNK / 4) {
            #pragma unroll
            for (int k = 0; k < 4; ++k) {
                long o2 = (long)((g + 1) * 4 + k) * stride + off;
                p4[k] = *(const f16x2*)(Pc + o2);
                s4[k] = *(const f16x2*)(ScInit + o2);
            }
        }
        #pragma unroll
        for (int k = 0; k < 4; ++k) {
            long o = (long)(g * 4 + k) * stride + off;
            *(f16x2*)(ScInit + o) = f16x2{(_Float16)c0, (_Float16)c1};
            c0 = c0 * (float)pc[k][0] + (float)sc[k][0];
            c1 = c1 * (float)pc[k][1] + (float)sc[k][1];
        }
    }
}

__global__ __launch_bounds__(256)
void scan_pass3_kernel(const _Float16* __restrict__ dtf, const float* __restrict__ ssm,
                       const _Float16* __restrict__ u16, const _Float16* __restrict__ proj,
                       const float* __restrict__ A_log, const float* __restrict__ Dp,
                       const _Float16* __restrict__ Init, _Float16* __restrict__ y16) {
    const int c = blockIdx.y;
    const int i0 = (blockIdx.x * 256 + threadIdx.x) * 2;

    __shared__ float Bs[TCHUNK * 16];
    __shared__ float Cs[TCHUNK * 16];
    for (int idx = threadIdx.x; idx < TCHUNK * 16; idx += 256) {
        int t = idx >> 4, n = idx & 15;
        Bs[idx] = ssm[(c * TCHUNK + t) * GDIM + RRANK + n];
        Cs[idx] = ssm[(c * TCHUNK + t) * GDIM + RRANK + NSTATE + n];
    }
    __syncthreads();

    float A[2][16];
    #pragma unroll
    for (int ch = 0; ch < 2; ++ch) {
        const float4* Ap = (const float4*)(A_log + (long)(i0 + ch) * 16);
        #pragma unroll
        for (int q = 0; q < 4; ++q) {
            float4 v = Ap[q];
            A[ch][q * 4 + 0] = -__expf(v.x);
            A[ch][q * 4 + 1] = -__expf(v.y);
            A[ch][q * 4 + 2] = -__expf(v.z);
            A[ch][q * 4 + 3] = -__expf(v.w);
        }
    }
    float2 Dv = *(const float2*)(Dp + i0);

    float s[2][16];
    {
        long o = ((long)c * IDIM + i0) * 16;
        #pragma unroll
        for (int ch = 0; ch < 2; ++ch)
            #pragma unroll
            for (int q = 0; q < 2; ++q) {
                f16x8 v = *(const f16x8*)(Init + o + ch * 16 + q * 8);
                #pragma unroll
                for (int e = 0; e < 8; ++e) s[ch][q * 8 + e] = (float)v[e];
            }
    }

    long base = (long)c * TCHUNK * IDIM + i0;
    for (int t = 0; t < TCHUNK; ++t) {
        f16x2 dt2 = *(const f16x2*)(dtf + base + (long)t * IDIM);
        f16x2 u2  = *(const f16x2*)(u16 + base + (long)t * IDIM);
        int tg = c * TCHUNK + t;
        f16x2 g2 = *(const f16x2*)(proj + (long)tg * (2 * IDIM) + IDIM + i0);
        f16x2 res;
        #pragma unroll
        for (int ch = 0; ch < 2; ++ch) {
            float dt = (float)dt2[ch];
            float uv = (float)u2[ch];
            float dtu = dt * uv;
            float y = 0.f;
            #pragma unroll
            for (int n = 0; n < 16; ++n) {
                float dA = __expf(dt * A[ch][n]);
                s[ch][n] = s[ch][n] * dA + dtu * Bs[t * 16 + n];
                y += s[ch][n] * Cs[t * 16 + n];
            }
            float g = (float)g2[ch];
            float Dch = ch ? Dv.y : Dv.x;
            res[ch] = (_Float16)((y + uv * Dch) * silu_f(g));
        }
        *(f16x2*)(y16 + base + (long)t * IDIM) = res;
    }
}

// ---------------------------------------------------------------------------
extern "C" void kernel_launch(void* const* d_in, const int* in_sizes, int n_in,
                              void* d_out, int out_size, void* d_ws, size_t ws_size,
                              hipStream_t stream) {
    const float* x_in  = (const float*)d_in[0];
    const float* w_in  = (const float*)d_in[1];
    const float* cw    = (const float*)d_in[2];
    const float* cb    = (const float*)d_in[3];
    const float* xw    = (const float*)d_in[4];
    const float* dtw   = (const float*)d_in[5];
    const float* dtb   = (const float*)d_in[6];
    const float* alog  = (const float*)d_in[7];
    const float* Dp    = (const float*)d_in[8];
    const float* ow    = (const float*)d_in[9];
    float* out = (float*)d_out;

    char* p = (char*)d_ws;
    auto alloc = [&](size_t bytes) { char* r = p; p += (bytes + 255) & ~255ull; return r; };
    _Float16* Xf    = (_Float16*)alloc((size_t)LSEQ * HID * 2);
    _Float16* Wt1   = (_Float16*)alloc((size_t)2 * IDIM * HID * 2);      // (2I,H); dead after in_proj
    _Float16* proj  = (_Float16*)alloc((size_t)LSEQ * 2 * IDIM * 2);
    _Float16* u16   = (_Float16*)alloc((size_t)LSEQ * IDIM * 2);
    _Float16* Wt2   = (_Float16*)alloc((size_t)256 * IDIM * 2);          // (GDIM pad 256, I)
    float*    ssm   = (float*)alloc((size_t)LSEQ * GDIM * 4);
    _Float16* dtin  = (_Float16*)alloc((size_t)LSEQ * RRANK * 2);
    _Float16* Wt3   = (_Float16*)alloc((size_t)IDIM * RRANK * 2);        // (I,R)
    _Float16* dtf   = (_Float16*)alloc((size_t)LSEQ * IDIM * 2);
    _Float16* Wt4   = (_Float16*)alloc((size_t)HID * IDIM * 2);          // (H,I)
    _Float16* y16   = (_Float16*)alloc((size_t)LSEQ * IDIM * 2);

    // aliases into dead Wt1 region (33.5 MB), lifetime-ordered:
    //   xpart f32 x16 (xproj) -> Pc/Sc f16 (scan)
    float* xpart = (float*)Wt1;                        // 16 x 2048 x 256 f32 = 33.5 MB (exact)
    _Float16* Pc = (_Float16*)Wt1;                     // G*I*16 f16 = 8.4 MB
    _Float16* Sc = Pc + (size_t)GCHUNK * IDIM * 16;    // 8.4 MB
    // out_proj f32 partials x4 = 67.1 MB: span proj..dtf (72.1 MB), all of
    // {proj,u16,Wt2,ssm,dtin,Wt3,dtf} dead after scan_pass3. Wt4/y16 live after.
    float* opart32 = (float*)proj;

    // 1. prep: all transposes (Wt1..Wt4) + X convert, BW-bound high-occupancy
    prep_kernel<<<7488, 256, 0, stream>>>(x_in, w_in, xw, dtw, ow,
                                          Xf, Wt1, Wt2, Wt3, Wt4);
    // 2. in_proj 256^2 pipelined GEMM (256 blocks, 1/CU)
    inproj256_kernel<<<256, 512, 0, stream>>>(Xf, Wt1, proj);
    // 3. conv + SiLU -> u16
    conv_silu_kernel<<<(LSEQ / 4) * (IDIM / 8) / 256, 256, 0, stream>>>(proj, cw, cb, u16);
    // 4. x_proj split-K x16: (L,I)@(I,256pad) -> partials
    gemm_bt_kernel<float, false><<<dim3(2, LSEQ / BM, 16), 256, 0, stream>>>(
        u16, Wt2, xpart, LSEQ, 256, IDIM, IDIM / 16, nullptr);
    xproj_reduce_kernel<<<(LSEQ * GDIM + 255) / 256, 256, 0, stream>>>(xpart, ssm, dtin);
    // 5. dt_proj (+bias+softplus): (L,R)@(R,I) -> dtf f16
    gemm_bt_kernel<_Float16, true><<<dim3(IDIM / 128, LSEQ / BM, 1), 256, 0, stream>>>(
        dtin, Wt3, dtf, LSEQ, IDIM, RRANK, RRANK, dtb);
    // 6. chunked scan
    scan_pass1_kernel<<<dim3(IDIM / 512, GCHUNK), 256, 0, stream>>>(
        dtf, ssm, u16, alog, Pc, Sc);
    scan_combine_kernel<<<(IDIM * NSTATE / 2) / 256, 256, 0, stream>>>(Pc, Sc);
    scan_pass3_kernel<<<dim3(IDIM / 512, GCHUNK), 256, 0, stream>>>(
        dtf, ssm, u16, proj, alog, Dp, Sc, y16);
    // 7. out_proj 256^2 pipelined GEMM, split-K x4 (f32 partials) -> reduce
    gemm256_kernel<<<dim3(HID / 256, LSEQ / 256, 4), 512, 0, stream>>>(
        y16, Wt4, opart32, LSEQ, HID, IDIM, IDIM / 4);
    opart_reduce_kernel<<<(LSEQ * HID / 32) / 256, 256, 0, stream>>>(opart32, out);
}

// Round 4
// 454.305 us; speedup vs baseline: 1.0433x; 1.0433x over previous
//
#include <hip/hip_runtime.h>
#include <stdint.h>

// Mamba-1.4B-like dims (fixed)
#define LSEQ 2048
#define HID  2048
#define IDIM 4096
#define NSTATE 16
#define RRANK 128
#define GDIM 160   // RRANK + 2*NSTATE

// chunked scan
#define GCHUNK 64
#define TCHUNK (LSEQ / GCHUNK)   // 32

typedef _Float16 f16x8 __attribute__((ext_vector_type(8)));
typedef _Float16 f16x2 __attribute__((ext_vector_type(2)));
typedef float f32x4 __attribute__((ext_vector_type(4)));

#define GLOAD_LDS16(g, l) __builtin_amdgcn_global_load_lds( \
    (const __attribute__((address_space(1))) void*)(g),     \
    (__attribute__((address_space(3))) void*)(l), 16, 0, 0)

__device__ __forceinline__ float softplus_f(float x) {
    if (x > 20.f) return x;
    return log1pf(__expf(x));
}
__device__ __forceinline__ float silu_f(float x) {
    return x / (1.f + __expf(-x));
}

// ---------------------------------------------------------------------------
// transpose one 64x64 tile of f32 (R x C) -> f16 (C x R)
__device__ __forceinline__ void transpose_tile(const float* __restrict__ in,
                                               _Float16* __restrict__ out,
                                               int R, int C, int tr, int tc,
                                               _Float16 (*tile)[66], int t) {
    const int c0 = tc * 64, r0 = tr * 64;
    const int tx = t & 15, ty = t >> 4;
    const int ox = t & 7, oy = t >> 3;
    const bool full = (c0 + 64 <= C) && (r0 + 64 <= R);
    if (full) {
        #pragma unroll
        for (int j = 0; j < 4; ++j) {
            int r = ty + j * 16;
            float4 v = *(const float4*)(in + (long)(r0 + r) * C + c0 + tx * 4);
            tile[r][tx * 4 + 0] = (_Float16)v.x;
            tile[r][tx * 4 + 1] = (_Float16)v.y;
            tile[r][tx * 4 + 2] = (_Float16)v.z;
            tile[r][tx * 4 + 3] = (_Float16)v.w;
        }
        __syncthreads();
        #pragma unroll
        for (int j = 0; j < 2; ++j) {
            int c = oy + j * 32;
            f16x8 v;
            #pragma unroll
            for (int e = 0; e < 8; ++e) v[e] = tile[ox * 8 + e][c];
            *(f16x8*)(out + (long)(c0 + c) * R + r0 + ox * 8) = v;
        }
    } else {
        #pragma unroll
        for (int j = 0; j < 4; ++j) {
            int r = ty + j * 16;
            #pragma unroll
            for (int e = 0; e < 4; ++e) {
                int c = c0 + tx * 4 + e;
                float v = (r0 + r < R && c < C) ? in[(long)(r0 + r) * C + c] : 0.f;
                tile[r][tx * 4 + e] = (_Float16)v;
            }
        }
        __syncthreads();
        #pragma unroll
        for (int j = 0; j < 2; ++j) {
            int c = c0 + oy + j * 32;
            if (c < C) {
                #pragma unroll
                for (int e = 0; e < 8; ++e) {
                    int r = r0 + ox * 8 + e;
                    if (r < R) out[(long)c * R + r] = tile[ox * 8 + e][oy + j * 32];
                }
            }
        }
    }
}

// ---------------------------------------------------------------------------
// prep: ALL transposes (Wt1/Wt2/Wt3/Wt4) + X f32->f16, high-occupancy BW-bound.
// 4096 + 1024 + 192 + 128 + 2048 = 7488 blocks.
__global__ __launch_bounds__(256)
void prep_kernel(const float* __restrict__ x_in, const float* __restrict__ w_in,
                 const float* __restrict__ xw, const float* __restrict__ dtw,
                 const float* __restrict__ ow,
                 _Float16* __restrict__ Xf, _Float16* __restrict__ Wt1,
                 _Float16* __restrict__ Wt2, _Float16* __restrict__ Wt3,
                 _Float16* __restrict__ Wt4) {
    __shared__ _Float16 tile[64][66];
    int b = blockIdx.x;
    if (b < 4096) { transpose_tile(w_in, Wt1, HID, 2 * IDIM, b / 128, b % 128, tile, threadIdx.x); return; }
    b -= 4096;
    if (b < 1024) {
        long base = (long)b * 4096 + threadIdx.x * 16;
        #pragma unroll
        for (int h = 0; h < 2; ++h) {
            float4 a = *(const float4*)(x_in + base + h * 8);
            float4 c = *(const float4*)(x_in + base + h * 8 + 4);
            f16x8 v;
            v[0] = (_Float16)a.x; v[1] = (_Float16)a.y; v[2] = (_Float16)a.z; v[3] = (_Float16)a.w;
            v[4] = (_Float16)c.x; v[5] = (_Float16)c.y; v[6] = (_Float16)c.z; v[7] = (_Float16)c.w;
            *(f16x8*)(Xf + base + h * 8) = v;
        }
        return;
    }
    b -= 1024;
    if (b < 192) { transpose_tile(xw, Wt2, IDIM, GDIM, b / 3, b % 3, tile, threadIdx.x); return; }
    b -= 192;
    if (b < 128) { transpose_tile(dtw, Wt3, RRANK, IDIM, b / 64, b % 64, tile, threadIdx.x); return; }
    b -= 128;
    transpose_tile(ow, Wt4, IDIM, HID, b / 32, b % 32, tile, threadIdx.x);
}

// ---------------------------------------------------------------------------
// OLD GEMM core (kept for xproj / dtproj skinny shapes):
// C = A(M,K) @ Bt(N,K)^T, fp16 in, fp32 acc. BM=128, BN=128, BK=64.
#define BM 128
#define BK 64

template <typename CT, bool SOFTPLUS>
__device__ __forceinline__
void gemm_core(const _Float16* __restrict__ A, const _Float16* __restrict__ Bt,
               CT* __restrict__ C, int M, int N, int K, int kc,
               const float* __restrict__ bias,
               _Float16* __restrict__ As, _Float16* __restrict__ Bs,
               int m0, int n0, int zz) {
    const int t = threadIdx.x;
    const int wave = t >> 6;
    const int lane = t & 63;
    const int wm = wave >> 1, wn = wave & 1;
    const int lrow = lane & 15;
    const int quad = lane >> 4;
    const int sw8 = (lrow & 7) * 8;

    f32x4 acc[4][4];
    #pragma unroll
    for (int mi = 0; mi < 4; ++mi)
        #pragma unroll
        for (int ni = 0; ni < 4; ++ni)
            #pragma unroll
            for (int r = 0; r < 4; ++r)
                acc[mi][ni][r] = 0.f;

    const int k_begin = zz * kc;
    const _Float16* pA[4];
    const _Float16* pB[4];
    #pragma unroll
    for (int j = 0; j < 4; ++j) {
        int s = j * 256 + t;
        int row = s >> 3;
        int ch = (s & 7) ^ (row & 7);
        pA[j] = A + (long)(m0 + row) * K + ch * 8 + k_begin;
        pB[j] = Bt + (long)(n0 + row) * K + ch * 8 + k_begin;
    }

    for (int kk = 0; kk < kc; kk += BK) {
        #pragma unroll
        for (int j = 0; j < 4; ++j) {
            GLOAD_LDS16(pA[j], As + (j * 256 + wave * 64) * 8);
            pA[j] += BK;
            GLOAD_LDS16(pB[j], Bs + (j * 256 + wave * 64) * 8);
            pB[j] += BK;
        }
        __syncthreads();

        #pragma unroll
        for (int h = 0; h < 2; ++h) {
            const int qoff = (h * 32 + quad * 8) ^ sw8;
            f16x8 af[4], bf[4];
            #pragma unroll
            for (int mi = 0; mi < 4; ++mi)
                af[mi] = *(const f16x8*)(As + (wm * 64 + mi * 16 + lrow) * BK + qoff);
            #pragma unroll
            for (int ni = 0; ni < 4; ++ni)
                bf[ni] = *(const f16x8*)(Bs + (wn * 64 + ni * 16 + lrow) * BK + qoff);
            #pragma unroll
            for (int mi = 0; mi < 4; ++mi)
                #pragma unroll
                for (int ni = 0; ni < 4; ++ni)
                    acc[mi][ni] = __builtin_amdgcn_mfma_f32_16x16x32_f16(af[mi], bf[ni], acc[mi][ni], 0, 0, 0);
        }
        __syncthreads();
    }

    CT* Cz = C + (long)zz * M * N;
    #pragma unroll
    for (int mi = 0; mi < 4; ++mi) {
        #pragma unroll
        for (int ni = 0; ni < 4; ++ni) {
            int col = n0 + wn * 64 + ni * 16 + lrow;
            if (col < N) {
                float bv = SOFTPLUS ? bias[col] : 0.f;
                #pragma unroll
                for (int r = 0; r < 4; ++r) {
                    int row = m0 + wm * 64 + mi * 16 + quad * 4 + r;
                    float v = acc[mi][ni][r];
                    if (SOFTPLUS) v = softplus_f(v + bv);
                    Cz[(long)row * N + col] = (CT)v;
                }
            }
        }
    }
}

// standalone GEMM wrapper (xproj / dtproj)
template <typename CT, bool SOFTPLUS>
__global__ __launch_bounds__(256)
void gemm_bt_kernel(const _Float16* __restrict__ A, const _Float16* __restrict__ Bt,
                    CT* __restrict__ C, int M, int N, int K, int kc,
                    const float* __restrict__ bias) {
    __shared__ _Float16 As[BM * BK];
    __shared__ _Float16 Bs[128 * BK];
    gemm_core<CT, SOFTPLUS>(A, Bt, C, M, N, K, kc, bias, As, Bs,
                            blockIdx.y * BM, blockIdx.x * 128, blockIdx.z);
}

// ---------------------------------------------------------------------------
// 256x256 deep-pipelined GEMM core, ring of 4 K=32 slices, counted vmcnt(8).
// VERIFIED round-2 body (74 us inproj, BANK_CONFLICT=0). The 2-phase split
// variant (round 3) is quarantined pending a race-screen.
// LDS layout (per slice, per operand, 8192 elem): 128 lines x 64 elem (128B).
// Line l holds rows {2l, 2l+1}; 16B sub-chunk s of line l holds (parity p,
// k-chunk c) with (c + 4p) = s ^ (l & 7). Conflict-free on ds_read_b128 and
// linear on the gload_lds dest (inverse perm baked into global source addr).
template <typename CT>
__device__ __forceinline__
void gemm256_core(const _Float16* __restrict__ A, const _Float16* __restrict__ Bt,
                  CT* __restrict__ C, int M, int N, int K, int kc,
                  int m0, int n0, int zz, _Float16* __restrict__ sm) {
    const int t = threadIdx.x;
    const int wave = t >> 6, lane = t & 63;
    const int wm = wave >> 2, wn = wave & 3;
    const int lrow = lane & 15, quad = lane >> 4;
    const int ns = kc >> 5;              // K=32 slices

    // staging source: thread t stages line l0 = t>>3, sub-chunk s = t&7
    const int l0 = t >> 3;                         // 0..63
    const int e  = (t & 7) ^ (l0 & 7);             // = c + 4p
    const int sp = e >> 2, sc = e & 3;             // parity, k-chunk
    const int rowA = 2 * l0 + sp;                  // pass-0 tile row
    const _Float16* gA0 = A  + (size_t)(m0 + rowA) * K + (size_t)zz * kc + sc * 8;
    const _Float16* gA1 = gA0 + (size_t)128 * K;   // pass-1 (rows +128)
    const _Float16* gB0 = Bt + (size_t)(n0 + rowA) * K + (size_t)zz * kc + sc * 8;
    const _Float16* gB1 = gB0 + (size_t)128 * K;

    _Float16* const bsm = sm + 32768;    // B region (elements)
    const int dA = wave * 512;           // wave-uniform LDS dest (elements)

    f32x4 acc[8][4];
    #pragma unroll
    for (int mi = 0; mi < 8; ++mi)
        #pragma unroll
        for (int ni = 0; ni < 4; ++ni)
            #pragma unroll
            for (int r = 0; r < 4; ++r) acc[mi][ni][r] = 0.f;

    #define ISSUE_SLICE(slot) do {                                          \
        _Float16* as_ = sm  + (slot) * 8192;                                \
        _Float16* bs_ = bsm + (slot) * 8192;                                \
        GLOAD_LDS16(gA0, as_ + dA);                                         \
        GLOAD_LDS16(gA1, as_ + 4096 + dA);                                  \
        GLOAD_LDS16(gB0, bs_ + dA);                                         \
        GLOAD_LDS16(gB1, bs_ + 4096 + dA);                                  \
        gA0 += 32; gA1 += 32; gB0 += 32; gB1 += 32;                         \
    } while (0)

    // prologue: 3 slices in flight, wait slice 0 (8 newer loads outstanding)
    ISSUE_SLICE(0); ISSUE_SLICE(1); ISSUE_SLICE(2);
    asm volatile("s_waitcnt vmcnt(8)" ::: "memory");
    __builtin_amdgcn_s_barrier();
    __builtin_amdgcn_sched_barrier(0);

    const int hl = lrow >> 1;                                    // 0..7
    const int koff = ((quad + 4 * (lrow & 1)) ^ hl) * 8;         // swizzled 16B slot
    const int arow0 = wm * 4096 + hl * 64 + koff;
    const int brow0 = wn * 2048 + hl * 64 + koff;

    for (int s2 = 0; s2 < ns; ++s2) {
        const _Float16* as_ = sm  + (s2 & 3) * 8192;
        const _Float16* bs_ = bsm + (s2 & 3) * 8192;
        if (s2 + 3 < ns) ISSUE_SLICE((s2 + 3) & 3);
        __builtin_amdgcn_sched_barrier(0);   // pin issue before ds_reads

        f16x8 af[8], bf[4];
        #pragma unroll
        for (int mi = 0; mi < 8; ++mi)
            af[mi] = *(const f16x8*)(as_ + arow0 + mi * 512);
        #pragma unroll
        for (int ni = 0; ni < 4; ++ni)
            bf[ni] = *(const f16x8*)(bs_ + brow0 + ni * 512);

        __builtin_amdgcn_s_setprio(1);
        #pragma unroll
        for (int mi = 0; mi < 8; ++mi)
            #pragma unroll
            for (int ni = 0; ni < 4; ++ni)
                acc[mi][ni] = __builtin_amdgcn_mfma_f32_16x16x32_f16(af[mi], bf[ni], acc[mi][ni], 0, 0, 0);
        __builtin_amdgcn_s_setprio(0);

        if (s2 + 1 < ns) {
            // need slice s2+1 landed; issued through slice min(s2+3, ns-1)
            if (s2 + 4 <= ns)      asm volatile("s_waitcnt vmcnt(8)" ::: "memory");
            else if (s2 + 3 == ns) asm volatile("s_waitcnt vmcnt(4)" ::: "memory");
            else                   asm volatile("s_waitcnt vmcnt(0)" ::: "memory");
            __builtin_amdgcn_s_barrier();
            __builtin_amdgcn_sched_barrier(0);
        }
    }
    #undef ISSUE_SLICE

    CT* Cz = C + (size_t)zz * ((size_t)M * N);
    const int crow = m0 + wm * 128 + quad * 4;
    const int ccol = n0 + wn * 64 + lrow;
    #pragma unroll
    for (int mi = 0; mi < 8; ++mi)
        #pragma unroll
        for (int ni = 0; ni < 4; ++ni)
            #pragma unroll
            for (int r = 0; r < 4; ++r)
                Cz[(size_t)(crow + mi * 16 + r) * N + ccol + ni * 16] = (CT)acc[mi][ni][r];
}

// split-K wrapper: grid dim3(N/256, M/256, Z)
template <typename CT>
__global__ __launch_bounds__(512, 2)
void gemm256_kernel(const _Float16* __restrict__ A, const _Float16* __restrict__ Bt,
                    CT* __restrict__ C, int M, int N, int K, int kc) {
    __shared__ _Float16 sm[65536];   // 128 KiB
    int nb = gridDim.x * gridDim.y * gridDim.z;
    int f0 = blockIdx.x + gridDim.x * (blockIdx.y + gridDim.y * blockIdx.z);
    int cpx = nb >> 3;                              // blocks per XCD (nb % 8 == 0)
    int f = (f0 & 7) * cpx + (f0 >> 3);             // bijective XCD swizzle
    int bx = f % gridDim.x;
    int r2 = f / gridDim.x;
    int by = r2 % gridDim.y;
    int bz = r2 / gridDim.y;
    gemm256_core<CT>(A, Bt, C, M, N, K, kc, by * 256, bx * 256, bz, sm);
}

// in_proj: pure 256-block 256^2 GEMM (1 block/CU)
__global__ __launch_bounds__(512, 2)
void inproj256_kernel(const _Float16* __restrict__ Xf, const _Float16* __restrict__ Wt1,
                      _Float16* __restrict__ proj) {
    __shared__ _Float16 sm[65536];   // 128 KiB
    int b = blockIdx.x;
    // XCD swizzle: XCD x owns tile-row x (A-panel stays in its L2)
    int f = (b & 7) * 32 + (b >> 3);
    gemm256_core<_Float16>(Xf, Wt1, proj, LSEQ, 2 * IDIM, HID, HID,
                           (f >> 5) * 256, (f & 31) * 256, 0, sm);
}

// ---------------------------------------------------------------------------
// x_proj split-K reduce: sum 8 partial slabs (L,256), write ssm (L,160) f32
// and dt_in (L,128) f16.
__global__ void xproj_reduce_kernel(const float* __restrict__ part, float* __restrict__ ssm,
                                    _Float16* __restrict__ dtin) {
    int idx = blockIdx.x * 256 + threadIdx.x;
    if (idx >= LSEQ * GDIM) return;
    int t = idx / GDIM;
    int c = idx - t * GDIM;
    float v = 0.f;
    #pragma unroll
    for (int k = 0; k < 8; ++k)
        v += part[((long)k * LSEQ + t) * 256 + c];
    ssm[idx] = v;
    if (c < RRANK) dtin[t * RRANK + c] = (_Float16)v;
}

// ---------------------------------------------------------------------------
// out_proj split-K reduce (f16 partials x4): out = p0+p1+p2+p3 -> f32
__global__ void opart_reduce_kernel(const _Float16* __restrict__ part, float* __restrict__ out) {
    long base = ((long)blockIdx.x * 256 + threadIdx.x) * 32;
    const long SL = (long)LSEQ * HID;
    #pragma unroll
    for (int j = 0; j < 4; ++j) {
        f16x8 a = *(const f16x8*)(part + base + j * 8);
        f16x8 b = *(const f16x8*)(part + SL + base + j * 8);
        f16x8 c = *(const f16x8*)(part + 2 * SL + base + j * 8);
        f16x8 d = *(const f16x8*)(part + 3 * SL + base + j * 8);
        float4 o0 = make_float4((float)a[0] + (float)b[0] + (float)c[0] + (float)d[0],
                                (float)a[1] + (float)b[1] + (float)c[1] + (float)d[1],
                                (float)a[2] + (float)b[2] + (float)c[2] + (float)d[2],
                                (float)a[3] + (float)b[3] + (float)c[3] + (float)d[3]);
        float4 o1 = make_float4((float)a[4] + (float)b[4] + (float)c[4] + (float)d[4],
                                (float)a[5] + (float)b[5] + (float)c[5] + (float)d[5],
                                (float)a[6] + (float)b[6] + (float)c[6] + (float)d[6],
                                (float)a[7] + (float)b[7] + (float)c[7] + (float)d[7]);
        *(float4*)(out + base + j * 8) = o0;
        *(float4*)(out + base + j * 8 + 4) = o1;
    }
}

// ---------------------------------------------------------------------------
// depthwise causal conv (K=4) + bias + SiLU; 8 channels x 4 timesteps/thread
__global__ void conv_silu_kernel(const _Float16* __restrict__ proj, const float* __restrict__ w,
                                 const float* __restrict__ b, _Float16* __restrict__ u16) {
    int idx = blockIdx.x * 256 + threadIdx.x;   // (L/4) * (I/8)
    int i0 = (idx & 511) * 8;
    int t0 = (idx >> 9) * 4;
    f16x8 r[7];
    #pragma unroll
    for (int k = 0; k < 7; ++k) {
        int tt = t0 - 3 + k;
        if (tt >= 0) r[k] = *(const f16x8*)(proj + (long)tt * (2 * IDIM) + i0);
        else         r[k] = f16x8{0,0,0,0,0,0,0,0};
    }
    float4 wv[8]; float bb[8];
    #pragma unroll
    for (int j = 0; j < 8; ++j) { wv[j] = ((const float4*)w)[i0 + j]; bb[j] = b[i0 + j]; }
    #pragma unroll
    for (int tt = 0; tt < 4; ++tt) {
        f16x8 res;
        #pragma unroll
        for (int j = 0; j < 8; ++j) {
            float a = bb[j] + (float)r[tt][j] * wv[j].x + (float)r[tt+1][j] * wv[j].y
                            + (float)r[tt+2][j] * wv[j].z + (float)r[tt+3][j] * wv[j].w;
            res[j] = (_Float16)(a / (1.f + __expf(-a)));
        }
        *(f16x8*)(u16 + (long)(t0 + tt) * IDIM + i0) = res;
    }
}

// ---------------------------------------------------------------------------
// Chunked selective scan, 2 channels/thread, f16 chunk states.
__global__ __launch_bounds__(256)
void scan_pass1_kernel(const _Float16* __restrict__ dtf, const float* __restrict__ ssm,
                       const _Float16* __restrict__ u16, const float* __restrict__ A_log,
                       _Float16* __restrict__ Pc, _Float16* __restrict__ Sc) {
    const int c = blockIdx.y;
    const int i0 = (blockIdx.x * 256 + threadIdx.x) * 2;

    __shared__ float Bs[TCHUNK * 16];
    for (int idx = threadIdx.x; idx < TCHUNK * 16; idx += 256) {
        int t = idx >> 4, n = idx & 15;
        Bs[idx] = ssm[(c * TCHUNK + t) * GDIM + RRANK + n];
    }
    __syncthreads();

    float A[2][16];
    #pragma unroll
    for (int ch = 0; ch < 2; ++ch) {
        const float4* Ap = (const float4*)(A_log + (long)(i0 + ch) * 16);
        #pragma unroll
        for (int q = 0; q < 4; ++q) {
            float4 v = Ap[q];
            A[ch][q * 4 + 0] = -__expf(v.x);
            A[ch][q * 4 + 1] = -__expf(v.y);
            A[ch][q * 4 + 2] = -__expf(v.z);
            A[ch][q * 4 + 3] = -__expf(v.w);
        }
    }

    float s[2][16];
    float sumdt[2] = {0.f, 0.f};
    #pragma unroll
    for (int ch = 0; ch < 2; ++ch)
        #pragma unroll
        for (int n = 0; n < 16; ++n) s[ch][n] = 0.f;

    long base = (long)c * TCHUNK * IDIM + i0;
    for (int t = 0; t < TCHUNK; ++t) {
        f16x2 dt2 = *(const f16x2*)(dtf + base + (long)t * IDIM);
        f16x2 u2  = *(const f16x2*)(u16 + base + (long)t * IDIM);
        #pragma unroll
        for (int ch = 0; ch < 2; ++ch) {
            float dt = (float)dt2[ch];
            float dtu = dt * (float)u2[ch];
            sumdt[ch] += dt;
            #pragma unroll
            for (int n = 0; n < 16; ++n) {
                float dA = __expf(dt * A[ch][n]);
                s[ch][n] = s[ch][n] * dA + dtu * Bs[t * 16 + n];
            }
        }
    }

    long o = ((long)c * IDIM + i0) * 16;
    #pragma unroll
    for (int ch = 0; ch < 2; ++ch) {
        #pragma unroll
        for (int q = 0; q < 2; ++q) {
            f16x8 pv, sv;
            #pragma unroll
            for (int e = 0; e < 8; ++e) {
                pv[e] = (_Float16)__expf(A[ch][q * 8 + e] * sumdt[ch]);
                sv[e] = (_Float16)s[ch][q * 8 + e];
            }
            *(f16x8*)(Pc + o + ch * 16 + q * 8) = pv;
            *(f16x8*)(Sc + o + ch * 16 + q * 8) = sv;
        }
    }
}

// Combine: sequential over G chunks per (i,n) pair, f32 carry, group-of-4 prefetch.
__global__ void scan_combine_kernel(const _Float16* __restrict__ Pc, _Float16* __restrict__ ScInit) {
    int tid = blockIdx.x * 256 + threadIdx.x;   // I*16/2 pairs
    const long stride = (long)IDIM * 16;
    const long off = (long)tid * 2;
    f16x2 p4[4], s4[4];
    #pragma unroll
    for (int k = 0; k < 4; ++k) {
        p4[k] = *(const f16x2*)(Pc + (long)k * stride + off);
        s4[k] = *(const f16x2*)(ScInit + (long)k * stride + off);
    }
    float c0 = 0.f, c1 = 0.f;
    for (int g = 0; g < GCHUNK / 4; ++g) {
        f16x2 pc[4], sc[4];
        #pragma unroll
        for (int k = 0; k < 4; ++k) { pc[k] = p4[k]; sc[k] = s4[k]; }
        if (g + 1 < GCHUNK / 4) {
            #pragma unroll
            for (int k = 0; k < 4; ++k) {
                long o2 = (long)((g + 1) * 4 + k) * stride + off;
                p4[k] = *(const f16x2*)(Pc + o2);
                s4[k] = *(const f16x2*)(ScInit + o2);
            }
        }
        #pragma unroll
        for (int k = 0; k < 4; ++k) {
            long o = (long)(g * 4 + k) * stride + off;
            *(f16x2*)(ScInit + o) = f16x2{(_Float16)c0, (_Float16)c1};
            c0 = c0 * (float)pc[k][0] + (float)sc[k][0];
            c1 = c1 * (float)pc[k][1] + (float)sc[k][1];
        }
    }
}

__global__ __launch_bounds__(256)
void scan_pass3_kernel(const _Float16* __restrict__ dtf, const float* __restrict__ ssm,
                       const _Float16* __restrict__ u16, const _Float16* __restrict__ proj,
                       const float* __restrict__ A_log, const float* __restrict__ Dp,
                       const _Float16* __restrict__ Init, _Float16* __restrict__ y16) {
    const int c = blockIdx.y;
    const int i0 = (blockIdx.x * 256 + threadIdx.x) * 2;

    __shared__ float Bs[TCHUNK * 16];
    __shared__ float Cs[TCHUNK * 16];
    for (int idx = threadIdx.x; idx < TCHUNK * 16; idx += 256) {
        int t = idx >> 4, n = idx & 15;
        Bs[idx] = ssm[(c * TCHUNK + t) * GDIM + RRANK + n];
        Cs[idx] = ssm[(c * TCHUNK + t) * GDIM + RRANK + NSTATE + n];
    }
    __syncthreads();

    float A[2][16];
    #pragma unroll
    for (int ch = 0; ch < 2; ++ch) {
        const float4* Ap = (const float4*)(A_log + (long)(i0 + ch) * 16);
        #pragma unroll
        for (int q = 0; q < 4; ++q) {
            float4 v = Ap[q];
            A[ch][q * 4 + 0] = -__expf(v.x);
            A[ch][q * 4 + 1] = -__expf(v.y);
            A[ch][q * 4 + 2] = -__expf(v.z);
            A[ch][q * 4 + 3] = -__expf(v.w);
        }
    }
    float2 Dv = *(const float2*)(Dp + i0);

    float s[2][16];
    {
        long o = ((long)c * IDIM + i0) * 16;
        #pragma unroll
        for (int ch = 0; ch < 2; ++ch)
            #pragma unroll
            for (int q = 0; q < 2; ++q) {
                f16x8 v = *(const f16x8*)(Init + o + ch * 16 + q * 8);
                #pragma unroll
                for (int e = 0; e < 8; ++e) s[ch][q * 8 + e] = (float)v[e];
            }
    }

    long base = (long)c * TCHUNK * IDIM + i0;
    for (int t = 0; t < TCHUNK; ++t) {
        f16x2 dt2 = *(const f16x2*)(dtf + base + (long)t * IDIM);
        f16x2 u2  = *(const f16x2*)(u16 + base + (long)t * IDIM);
        int tg = c * TCHUNK + t;
        f16x2 g2 = *(const f16x2*)(proj + (long)tg * (2 * IDIM) + IDIM + i0);
        f16x2 res;
        #pragma unroll
        for (int ch = 0; ch < 2; ++ch) {
            float dt = (float)dt2[ch];
            float uv = (float)u2[ch];
            float dtu = dt * uv;
            float y = 0.f;
            #pragma unroll
            for (int n = 0; n < 16; ++n) {
                float dA = __expf(dt * A[ch][n]);
                s[ch][n] = s[ch][n] * dA + dtu * Bs[t * 16 + n];
                y += s[ch][n] * Cs[t * 16 + n];
            }
            float g = (float)g2[ch];
            float Dch = ch ? Dv.y : Dv.x;
            res[ch] = (_Float16)((y + uv * Dch) * silu_f(g));
        }
        *(f16x2*)(y16 + base + (long)t * IDIM) = res;
    }
}

// ---------------------------------------------------------------------------
extern "C" void kernel_launch(void* const* d_in, const int* in_sizes, int n_in,
                              void* d_out, int out_size, void* d_ws, size_t ws_size,
                              hipStream_t stream) {
    const float* x_in  = (const float*)d_in[0];
    const float* w_in  = (const float*)d_in[1];
    const float* cw    = (const float*)d_in[2];
    const float* cb    = (const float*)d_in[3];
    const float* xw    = (const float*)d_in[4];
    const float* dtw   = (const float*)d_in[5];
    const float* dtb   = (const float*)d_in[6];
    const float* alog  = (const float*)d_in[7];
    const float* Dp    = (const float*)d_in[8];
    const float* ow    = (const float*)d_in[9];
    float* out = (float*)d_out;

    char* p = (char*)d_ws;
    auto alloc = [&](size_t bytes) { char* r = p; p += (bytes + 255) & ~255ull; return r; };
    _Float16* Xf    = (_Float16*)alloc((size_t)LSEQ * HID * 2);
    _Float16* Wt1   = (_Float16*)alloc((size_t)2 * IDIM * HID * 2);      // (2I,H); dead after in_proj
    _Float16* proj  = (_Float16*)alloc((size_t)LSEQ * 2 * IDIM * 2);
    _Float16* u16   = (_Float16*)alloc((size_t)LSEQ * IDIM * 2);
    _Float16* Wt2   = (_Float16*)alloc((size_t)256 * IDIM * 2);          // (GDIM pad 256, I)
    float*    ssm   = (float*)alloc((size_t)LSEQ * GDIM * 4);
    _Float16* dtin  = (_Float16*)alloc((size_t)LSEQ * RRANK * 2);
    _Float16* Wt3   = (_Float16*)alloc((size_t)IDIM * RRANK * 2);        // (I,R)
    _Float16* dtf   = (_Float16*)alloc((size_t)LSEQ * IDIM * 2);
    _Float16* Wt4   = (_Float16*)alloc((size_t)HID * IDIM * 2);          // (H,I)
    _Float16* y16   = (_Float16*)alloc((size_t)LSEQ * IDIM * 2);

    // aliases into dead Wt1 region (33.5 MB), lifetime-ordered:
    //   xpart f32 x8 (xproj, 16.8 MB) -> Pc/Sc f16 (scan, 16.8 MB)
    //   -> opart f16 x4 (out_proj, 33.55 MB exact)
    float* xpart = (float*)Wt1;
    _Float16* Pc = (_Float16*)Wt1;                     // G*I*16 f16 = 8.4 MB
    _Float16* Sc = Pc + (size_t)GCHUNK * IDIM * 16;    // 8.4 MB
    _Float16* opart = (_Float16*)Wt1;                  // 4 x L*H f16 = 33.55 MB

    // 1. prep: all transposes (Wt1..Wt4) + X convert, BW-bound high-occupancy
    prep_kernel<<<7488, 256, 0, stream>>>(x_in, w_in, xw, dtw, ow,
                                          Xf, Wt1, Wt2, Wt3, Wt4);
    // 2. in_proj 256^2 pipelined GEMM (256 blocks, 1/CU)
    inproj256_kernel<<<256, 512, 0, stream>>>(Xf, Wt1, proj);
    // 3. conv + SiLU -> u16
    conv_silu_kernel<<<(LSEQ / 4) * (IDIM / 8) / 256, 256, 0, stream>>>(proj, cw, cb, u16);
    // 4. x_proj split-K x8: (L,I)@(I,256pad) -> partials
    gemm_bt_kernel<float, false><<<dim3(2, LSEQ / BM, 8), 256, 0, stream>>>(
        u16, Wt2, xpart, LSEQ, 256, IDIM, IDIM / 8, nullptr);
    xproj_reduce_kernel<<<(LSEQ * GDIM + 255) / 256, 256, 0, stream>>>(xpart, ssm, dtin);
    // 5. dt_proj (+bias+softplus): (L,R)@(R,I) -> dtf f16
    gemm_bt_kernel<_Float16, true><<<dim3(IDIM / 128, LSEQ / BM, 1), 256, 0, stream>>>(
        dtin, Wt3, dtf, LSEQ, IDIM, RRANK, RRANK, dtb);
    // 6. chunked scan
    scan_pass1_kernel<<<dim3(IDIM / 512, GCHUNK), 256, 0, stream>>>(
        dtf, ssm, u16, alog, Pc, Sc);
    scan_combine_kernel<<<(IDIM * NSTATE / 2) / 256, 256, 0, stream>>>(Pc, Sc);
    scan_pass3_kernel<<<dim3(IDIM / 512, GCHUNK), 256, 0, stream>>>(
        dtf, ssm, u16, proj, alog, Dp, Sc, y16);
    // 7. out_proj 256^2 pipelined GEMM, split-K x4 (f16 partials) -> reduce
    gemm256_kernel<_Float16><<<dim3(HID / 256, LSEQ / 256, 4), 512, 0, stream>>>(
        y16, Wt4, opart, LSEQ, HID, IDIM, IDIM / 4);
    opart_reduce_kernel<<<(LSEQ * HID / 32) / 256, 256, 0, stream>>>(opart, out);
}